// Round 1
// baseline (1304.858 us; speedup 1.0000x reference)
//
#include <hip/hip_runtime.h>
#include <stdint.h>

typedef __bf16 bf16;
typedef __bf16 bf16x8 __attribute__((ext_vector_type(8)));
typedef float f32x4 __attribute__((ext_vector_type(4)));

#define DEV __device__ __forceinline__

static constexpr int Dm   = 1024;
static constexpr int DFFm = 4096;
static constexpr int Tm   = 2048;   // B*S tokens
static constexpr int Vm   = 32000;

// ---------------- helpers ----------------
#define GLOAD_LDS16(g, l)                                                      \
  __builtin_amdgcn_global_load_lds(                                            \
      (const __attribute__((address_space(1))) unsigned int*)(g),              \
      (__attribute__((address_space(3))) unsigned int*)(l), 16, 0, 0)

// copy 128x32 bf16 tile from global (row stride ldg elems) into lds[128][32]
DEV void stage_tile(bf16* lds_t, const bf16* g, long ldg, int wid, int lane) {
#pragma unroll
  for (int p = 0; p < 2; ++p) {
    const int c = p * 256 + wid * 64 + lane;          // 16B chunk id, 0..511
    const bf16* src = g + (long)(c >> 2) * ldg + (c & 3) * 8;
    char* dst = (char*)lds_t + (p * 256 + wid * 64) * 16;  // wave-uniform base
    GLOAD_LDS16(src, dst);
  }
}

DEV float gelu_fast(float v) {  // tanh-approx gelu, fast exp (expert path)
  float u = 0.7978845608028654f * (v + 0.044715f * v * v * v);
  float e = __expf(2.0f * u);
  float t = 1.0f - 2.0f / (e + 1.0f);
  return 0.5f * v * (1.0f + t);
}
DEV float gelu_precise(float v) {  // temporal path feeds router: use tanhf
  float u = 0.7978845608028654f * (v + 0.044715f * v * v * v);
  return 0.5f * v * (1.0f + tanhf(u));
}

// ---------------- GEMM: C = A[M][K] * B^T ([N][K]) ----------------
enum { EPI_GELU_SPLIT = 0, EPI_RESID = 1, EPI_GELU_BF16 = 2, EPI_MOE = 3, EPI_BIAS = 4 };

struct GemmP {
  const bf16* Ah; const bf16* Al;
  const bf16* Bh; const bf16* Bl;
  const float* bias;
  const float* resid;
  const float* rwp;     // routing weights [T][8]
  float* outF;
  bf16* outH;
  bf16* outL;
  int K; int N;
  long aBS, bBS, outBS; // batch strides (elements) for blockIdx.z
  int biasBS;
  int ebase;            // expert base for MOE epilogue
};

template <int EPI, bool SPLIT>
__launch_bounds__(256, 2)
__global__ void gemm_bt(GemmP p) {
  constexpr int LDSN = SPLIT ? 4 : 2;
  __shared__ bf16 lds[LDSN * 4096];
  bf16* ldsAh = lds;
  bf16* ldsBh = lds + 4096;
  bf16* ldsAl = SPLIT ? lds + 8192 : lds;
  bf16* ldsBl = SPLIT ? lds + 12288 : lds;

  const int tid  = threadIdx.x;
  const int lane = tid & 63;
  const int wid  = tid >> 6;
  const int wr   = wid >> 1;   // 2x2 wave grid, each wave owns 64x64
  const int wc   = wid & 1;
  const int z    = blockIdx.z;
  const long K   = p.K;

  const long am0 = (long)blockIdx.y * 128;
  const long bn0 = (long)blockIdx.x * 128;

  const bf16* Ah = p.Ah + (long)z * p.aBS + am0 * K;
  const bf16* Bh = p.Bh + (long)z * p.bBS + bn0 * K;
  const bf16* Al = SPLIT ? (p.Al + (long)z * p.aBS + am0 * K) : Ah;
  const bf16* Bl = SPLIT ? (p.Bl + (long)z * p.bBS + bn0 * K) : Bh;

  f32x4 acc[4][4] = {};

  const int aoff = (wr * 64 + (lane & 15)) * 32 + (lane >> 4) * 8;
  const int boff = (wc * 64 + (lane & 15)) * 32 + (lane >> 4) * 8;

  for (long k0 = 0; k0 < K; k0 += 32) {
    __syncthreads();
    stage_tile(ldsAh, Ah + k0, K, wid, lane);
    stage_tile(ldsBh, Bh + k0, K, wid, lane);
    if constexpr (SPLIT) {
      stage_tile(ldsAl, Al + k0, K, wid, lane);
      stage_tile(ldsBl, Bl + k0, K, wid, lane);
    }
    __syncthreads();

    bf16x8 ah[4], bh[4];
#pragma unroll
    for (int m = 0; m < 4; ++m) ah[m] = *(const bf16x8*)(ldsAh + aoff + m * 512);
#pragma unroll
    for (int n = 0; n < 4; ++n) bh[n] = *(const bf16x8*)(ldsBh + boff + n * 512);
    if constexpr (SPLIT) {
      bf16x8 al[4], bl[4];
#pragma unroll
      for (int m = 0; m < 4; ++m) al[m] = *(const bf16x8*)(ldsAl + aoff + m * 512);
#pragma unroll
      for (int n = 0; n < 4; ++n) bl[n] = *(const bf16x8*)(ldsBl + boff + n * 512);
#pragma unroll
      for (int m = 0; m < 4; ++m)
#pragma unroll
        for (int n = 0; n < 4; ++n) {
          acc[m][n] = __builtin_amdgcn_mfma_f32_16x16x32_bf16(ah[m], bh[n], acc[m][n], 0, 0, 0);
          acc[m][n] = __builtin_amdgcn_mfma_f32_16x16x32_bf16(ah[m], bl[n], acc[m][n], 0, 0, 0);
          acc[m][n] = __builtin_amdgcn_mfma_f32_16x16x32_bf16(al[m], bh[n], acc[m][n], 0, 0, 0);
        }
    } else {
#pragma unroll
      for (int m = 0; m < 4; ++m)
#pragma unroll
        for (int n = 0; n < 4; ++n)
          acc[m][n] = __builtin_amdgcn_mfma_f32_16x16x32_bf16(ah[m], bh[n], acc[m][n], 0, 0, 0);
    }
  }

  const float* bias = p.bias + (long)z * p.biasBS;
  const long N = p.N;

#pragma unroll
  for (int m = 0; m < 4; ++m) {
#pragma unroll
    for (int n = 0; n < 4; ++n) {
      const long col = bn0 + wc * 64 + n * 16 + (lane & 15);
      const float bv = bias[col];
#pragma unroll
      for (int r = 0; r < 4; ++r) {
        const long row = am0 + wr * 64 + m * 16 + (lane >> 4) * 4 + r;
        float v = acc[m][n][r] + bv;
        if constexpr (EPI == EPI_GELU_SPLIT) {
          float g = gelu_precise(v);
          bf16 h = (bf16)g;
          long o = row * N + col;
          p.outH[o] = h;
          p.outL[o] = (bf16)(g - (float)h);
        } else if constexpr (EPI == EPI_RESID) {
          long o = row * N + col;
          p.outF[o] = p.resid[o] + v;   // in-place safe: 1 thread per element
        } else if constexpr (EPI == EPI_GELU_BF16) {
          long o = (long)z * p.outBS + row * N + col;
          p.outH[o] = (bf16)gelu_fast(v);
        } else if constexpr (EPI == EPI_MOE) {
          float wgt = p.rwp[row * 8 + p.ebase + z];
          if (wgt != 0.0f) atomicAdd(p.outF + row * N + col, wgt * v);
        } else {  // EPI_BIAS
          p.outF[row * N + col] = v;
        }
      }
    }
  }
}

// ------------- transpose fp32 [R][C] -> bf16 [C][R] (optional lo split) -------------
template <bool SPLITOUT>
__global__ void transpose_cvt(const float* __restrict__ in, bf16* __restrict__ outh,
                              bf16* __restrict__ outl, int R, int C, long inBS, long outBS) {
  __shared__ float tile[32][33];
  const float* inp = in + (long)blockIdx.z * inBS;
  const long c0 = (long)blockIdx.x * 32;
  const long r0 = (long)blockIdx.y * 32;
  const int tx = threadIdx.x;  // 32
  const int ty = threadIdx.y;  // 8
#pragma unroll
  for (int i = 0; i < 4; ++i) {
    int r = ty + i * 8;
    tile[r][tx] = inp[(r0 + r) * (long)C + c0 + tx];
  }
  __syncthreads();
  const long ob = (long)blockIdx.z * outBS;
#pragma unroll
  for (int i = 0; i < 4; ++i) {
    int c = ty + i * 8;
    float v = tile[tx][c];
    bf16 h = (bf16)v;
    long o = ob + (c0 + c) * (long)R + r0 + tx;
    outh[o] = h;
    if constexpr (SPLITOUT) outl[o] = (bf16)(v - (float)h);
  }
}

// ------------- embedding gather -------------
__global__ void embed_kernel(const int* __restrict__ ids, const float* __restrict__ emb,
                             float* __restrict__ x) {
  const long t = blockIdx.x;
  const int id = ids[t];
  ((float4*)(x + t * 1024))[threadIdx.x] = ((const float4*)(emb + (long)id * 1024))[threadIdx.x];
}

// ------------- LayerNorm -> bf16 hi/lo split -------------
__global__ void ln_split_kernel(const float* __restrict__ x, const float* __restrict__ sc,
                                const float* __restrict__ bi, bf16* __restrict__ oh,
                                bf16* __restrict__ ol) {
  const long t = blockIdx.x;
  const int tid = threadIdx.x;  // 256
  const int lane = tid & 63, wid = tid >> 6;
  float4 a = ((const float4*)(x + t * 1024))[tid];
  float s = a.x + a.y + a.z + a.w;
  float q = a.x * a.x + a.y * a.y + a.z * a.z + a.w * a.w;
#pragma unroll
  for (int off = 32; off; off >>= 1) {
    s += __shfl_down(s, off);
    q += __shfl_down(q, off);
  }
  __shared__ float sr[4], qr[4];
  if (lane == 0) { sr[wid] = s; qr[wid] = q; }
  __syncthreads();
  s = sr[0] + sr[1] + sr[2] + sr[3];
  q = qr[0] + qr[1] + qr[2] + qr[3];
  const float mu = s * (1.0f / 1024.0f);
  const float var = q * (1.0f / 1024.0f) - mu * mu;
  const float rs = rsqrtf(var + 1e-5f);
#pragma unroll
  for (int j = 0; j < 4; ++j) {
    const int d = tid * 4 + j;
    const float g = (((const float*)&a)[j] - mu) * rs * sc[d] + bi[d];
    const bf16 h = (bf16)g;
    oh[t * 1024 + d] = h;
    ol[t * 1024 + d] = (bf16)(g - (float)h);
  }
}

// ------------- router: logits, top-2 softmax, scatter -------------
__global__ void router_kernel(const float* __restrict__ x, const float* __restrict__ Wr,
                              const float* __restrict__ br, float* __restrict__ rwo) {
  const long t = blockIdx.x;
  const int lane = threadIdx.x;  // 64
  float acc[8];
#pragma unroll
  for (int e = 0; e < 8; ++e) acc[e] = 0.0f;
  const float4* xr = (const float4*)(x + t * 1024);
#pragma unroll
  for (int j = 0; j < 4; ++j) {
    const int d4 = j * 64 + lane;
    float4 xv = xr[d4];
#pragma unroll
    for (int u = 0; u < 4; ++u) {
      const float xs = ((const float*)&xv)[u];
      const float4* wp = (const float4*)(Wr + (long)(d4 * 4 + u) * 8);
      float4 w0 = wp[0], w1 = wp[1];
      acc[0] += xs * w0.x; acc[1] += xs * w0.y; acc[2] += xs * w0.z; acc[3] += xs * w0.w;
      acc[4] += xs * w1.x; acc[5] += xs * w1.y; acc[6] += xs * w1.z; acc[7] += xs * w1.w;
    }
  }
#pragma unroll
  for (int off = 32; off; off >>= 1)
#pragma unroll
    for (int e = 0; e < 8; ++e) acc[e] += __shfl_down(acc[e], off);
  if (lane == 0) {
    float v[8];
#pragma unroll
    for (int e = 0; e < 8; ++e) v[e] = acc[e] + br[e];
    int i0 = 0; float v0 = v[0];
    for (int e = 1; e < 8; ++e) if (v[e] > v0) { v0 = v[e]; i0 = e; }
    int i1 = -1; float v1 = -3.4e38f;
    for (int e = 0; e < 8; ++e) if (e != i0 && v[e] > v1) { v1 = v[e]; i1 = e; }
    float e1 = expf(v1 - v0);
    float den = 1.0f + e1;
    float w0 = 1.0f / den, w1 = e1 / den;
    float* o = rwo + t * 8;
#pragma unroll
    for (int e = 0; e < 8; ++e) o[e] = (e == i0) ? w0 : (e == i1 ? w1 : 0.0f);
  }
}

// ------------- fp32 -> bf16 flat convert -------------
__global__ void cvt_bf16_kernel(const float* __restrict__ in, bf16* __restrict__ out, long n) {
  long i = ((long)blockIdx.x * blockDim.x + threadIdx.x) * 8;
  if (i >= n) return;
  float4 a = *(const float4*)(in + i);
  float4 b = *(const float4*)(in + i + 4);
  bf16x8 o;
  o[0] = (bf16)a.x; o[1] = (bf16)a.y; o[2] = (bf16)a.z; o[3] = (bf16)a.w;
  o[4] = (bf16)b.x; o[5] = (bf16)b.y; o[6] = (bf16)b.z; o[7] = (bf16)b.w;
  *(bf16x8*)(out + i) = o;
}

// ---------------- host launch ----------------
extern "C" void kernel_launch(void* const* d_in, const int* in_sizes, int n_in,
                              void* d_out, int out_size, void* d_ws, size_t ws_size,
                              hipStream_t stream) {
  (void)in_sizes; (void)n_in; (void)out_size; (void)ws_size;
  const int*   ids  = (const int*)d_in[0];
  const float* emb  = (const float*)d_in[1];
  const float* tlns = (const float*)d_in[2];
  const float* tlnb = (const float*)d_in[3];
  const float* tw1  = (const float*)d_in[4];
  const float* tb1  = (const float*)d_in[5];
  const float* tw2  = (const float*)d_in[6];
  const float* tb2  = (const float*)d_in[7];
  const float* Wr   = (const float*)d_in[8];
  const float* br   = (const float*)d_in[9];
  const float* ew1  = (const float*)d_in[10];
  const float* eb1  = (const float*)d_in[11];
  const float* ew2  = (const float*)d_in[12];
  const float* eb2  = (const float*)d_in[13];
  const float* Wl   = (const float*)d_in[14];
  const float* bl   = (const float*)d_in[15];

  float* logits = (float*)d_out;
  float* rwout  = (float*)d_out + (long)Tm * Vm;

  // ws arena (~160 MiB) with phase-based region reuse
  size_t off = 0;
  auto take = [&](size_t bytes) {
    void* pp = (char*)d_ws + off;
    off += (bytes + 255) & ~(size_t)255;
    return pp;
  };
  float* X    = (float*)take((size_t)Tm * Dm * 4);
  bf16*  XB   = (bf16*) take((size_t)Tm * Dm * 2);
  float* Y    = (float*)take((size_t)Tm * Dm * 4);
  bf16*  YB   = (bf16*) take((size_t)Tm * Dm * 2);
  bf16*  Breg = (bf16*) take((size_t)4 * DFFm * Dm * 2);                 // 33.5MB
  bf16*  Creg = (bf16*) take((size_t)(2L * Tm * Dm + 2L * Tm * DFFm) * 2);  // 42MB
  bf16*  Dreg = (bf16*) take((size_t)4 * Tm * DFFm * 2);                 // 67MB

  bf16* TW1h = Breg;
  bf16* TW1l = Breg + (long)DFFm * Dm;
  bf16* TW2h = Breg + 2L * DFFm * Dm;
  bf16* TW2l = Breg + 3L * DFFm * Dm;
  bf16* EW1T = Breg;                 // reuse (4 experts x [4096][1024])
  bf16* HLNh = Creg;
  bf16* HLNl = Creg + (long)Tm * Dm;
  bf16* HTh  = Creg + 2L * Tm * Dm;
  bf16* HTl  = HTh + (long)Tm * DFFm;
  bf16* EW2T = Creg;                 // reuse (4 experts x [1024][4096])
  bf16* HE   = Dreg;                 // 4 experts x [2048][4096]
  bf16* WLT  = Dreg;                 // reuse: [32000][1024]

  embed_kernel<<<dim3(Tm), dim3(256), 0, stream>>>(ids, emb, X);

  // ---- temporal residual MLP blocks (fp32-accurate via bf16 hi/lo split) ----
  for (int l = 0; l < 2; ++l) {
    transpose_cvt<true><<<dim3(DFFm / 32, Dm / 32, 1), dim3(32, 8), 0, stream>>>(
        tw1 + (long)l * Dm * DFFm, TW1h, TW1l, Dm, DFFm, 0, 0);
    transpose_cvt<true><<<dim3(Dm / 32, DFFm / 32, 1), dim3(32, 8), 0, stream>>>(
        tw2 + (long)l * DFFm * Dm, TW2h, TW2l, DFFm, Dm, 0, 0);
    ln_split_kernel<<<dim3(Tm), dim3(256), 0, stream>>>(X, tlns + l * Dm, tlnb + l * Dm,
                                                        HLNh, HLNl);
    GemmP p1{};
    p1.Ah = HLNh; p1.Al = HLNl; p1.Bh = TW1h; p1.Bl = TW1l;
    p1.bias = tb1 + (long)l * DFFm;
    p1.outH = HTh; p1.outL = HTl;
    p1.K = Dm; p1.N = DFFm;
    gemm_bt<EPI_GELU_SPLIT, true><<<dim3(DFFm / 128, Tm / 128, 1), dim3(256), 0, stream>>>(p1);

    GemmP p2{};
    p2.Ah = HTh; p2.Al = HTl; p2.Bh = TW2h; p2.Bl = TW2l;
    p2.bias = tb2 + (long)l * Dm;
    p2.resid = X; p2.outF = X;
    p2.K = DFFm; p2.N = Dm;
    gemm_bt<EPI_RESID, true><<<dim3(Dm / 128, Tm / 128, 1), dim3(256), 0, stream>>>(p2);
  }

  // ---- router (fp32) ----
  router_kernel<<<dim3(Tm), dim3(64), 0, stream>>>(X, Wr, br, rwout);
  cvt_bf16_kernel<<<dim3(Tm * Dm / (256 * 8)), dim3(256), 0, stream>>>(X, XB, (long)Tm * Dm);
  hipMemsetAsync(Y, 0, (size_t)Tm * Dm * 4, stream);

  // ---- dense expert stack, 2 quads of 4 experts (bf16) ----
  for (int q = 0; q < 2; ++q) {
    transpose_cvt<false><<<dim3(DFFm / 32, Dm / 32, 4), dim3(32, 8), 0, stream>>>(
        ew1 + (long)q * 4 * Dm * DFFm, EW1T, nullptr, Dm, DFFm, (long)Dm * DFFm,
        (long)DFFm * Dm);
    transpose_cvt<false><<<dim3(Dm / 32, DFFm / 32, 4), dim3(32, 8), 0, stream>>>(
        ew2 + (long)q * 4 * DFFm * Dm, EW2T, nullptr, DFFm, Dm, (long)DFFm * Dm,
        (long)Dm * DFFm);

    GemmP pe1{};
    pe1.Ah = XB; pe1.Bh = EW1T;
    pe1.bias = eb1 + (long)q * 4 * DFFm; pe1.biasBS = DFFm;
    pe1.outH = HE; pe1.outBS = (long)Tm * DFFm;
    pe1.aBS = 0; pe1.bBS = (long)DFFm * Dm;
    pe1.K = Dm; pe1.N = DFFm;
    gemm_bt<EPI_GELU_BF16, false><<<dim3(DFFm / 128, Tm / 128, 4), dim3(256), 0, stream>>>(pe1);

    GemmP pe2{};
    pe2.Ah = HE; pe2.aBS = (long)Tm * DFFm;
    pe2.Bh = EW2T; pe2.bBS = (long)Dm * DFFm;
    pe2.bias = eb2 + (long)q * 4 * Dm; pe2.biasBS = Dm;
    pe2.rwp = rwout; pe2.ebase = q * 4;
    pe2.outF = Y;
    pe2.K = DFFm; pe2.N = Dm;
    gemm_bt<EPI_MOE, false><<<dim3(Dm / 128, Tm / 128, 4), dim3(256), 0, stream>>>(pe2);
  }

  // ---- final logits GEMM ----
  cvt_bf16_kernel<<<dim3(Tm * Dm / (256 * 8)), dim3(256), 0, stream>>>(Y, YB, (long)Tm * Dm);
  transpose_cvt<false><<<dim3(Vm / 32, Dm / 32, 1), dim3(32, 8), 0, stream>>>(
      Wl, WLT, nullptr, Dm, Vm, 0, 0);
  GemmP pl{};
  pl.Ah = YB; pl.Bh = WLT; pl.bias = bl;
  pl.outF = logits;
  pl.K = Dm; pl.N = Vm;
  gemm_bt<EPI_BIAS, false><<<dim3(Vm / 128, Tm / 128, 1), dim3(256), 0, stream>>>(pl);
}

// Round 2
// 1191.947 us; speedup vs baseline: 1.0947x; 1.0947x over previous
//
#include <hip/hip_runtime.h>
#include <stdint.h>

typedef __bf16 bf16;
typedef __bf16 bf16x8 __attribute__((ext_vector_type(8)));
typedef float f32x4 __attribute__((ext_vector_type(4)));

#define DEV __device__ __forceinline__

static constexpr int Dm   = 1024;
static constexpr int DFFm = 4096;
static constexpr int Tm   = 2048;   // B*S tokens
static constexpr int Vm   = 32000;

// ---------------- helpers ----------------
#define GLOAD_LDS16(g, l)                                                      \
  __builtin_amdgcn_global_load_lds(                                            \
      (const __attribute__((address_space(1))) unsigned int*)(g),              \
      (__attribute__((address_space(3))) unsigned int*)(l), 16, 0, 0)

DEV float gelu_fast(float v) {  // tanh-approx gelu, fast exp (expert path)
  float u = 0.7978845608028654f * (v + 0.044715f * v * v * v);
  float e = __expf(2.0f * u);
  float t = 1.0f - 2.0f / (e + 1.0f);
  return 0.5f * v * (1.0f + t);
}
DEV float gelu_precise(float v) {  // temporal path feeds router: use tanhf
  float u = 0.7978845608028654f * (v + 0.044715f * v * v * v);
  return 0.5f * v * (1.0f + tanhf(u));
}

// ---------------- GEMM: C = A[M][K] * B^T ([N][K]) ----------------
enum { EPI_GELU_SPLIT = 0, EPI_RESID = 1, EPI_GELU_BF16 = 2, EPI_MOE = 3, EPI_BIAS = 4 };

struct GemmP {
  const bf16* Ah; const bf16* Al;
  const bf16* Bh; const bf16* Bl;
  const float* bias;
  const float* resid;
  const float* rwp;     // routing weights [T][8]
  const int* cnt;       // per-expert token counts [8]
  const int* idx;       // per-expert token lists [8][2048]
  float* outF;
  bf16* outH;
  bf16* outL;
  int K; int N;
  long aBS, bBS, outBS; // batch strides (elements) for blockIdx.z
  int biasBS;
  int ebase;            // global expert base for this dispatch's z=0
};

template <int EPI, bool SPLIT, bool GATHER, bool SWZ>
__launch_bounds__(256, 2)
__global__ void gemm_bt(GemmP p) {
  constexpr bool SPARSE = GATHER || (EPI == EPI_MOE);
  constexpr int LDSN = SPLIT ? 4 : 2;
  __shared__ bf16 lds[LDSN * 4096];
  bf16* ldsAh = lds;
  bf16* ldsBh = lds + 4096;
  bf16* ldsAl = SPLIT ? lds + 8192 : lds;
  bf16* ldsBl = SPLIT ? lds + 12288 : lds;

  const int tid  = threadIdx.x;
  const int lane = tid & 63;
  const int wid  = tid >> 6;
  const int wr   = wid >> 1;   // 2x2 wave grid, each wave owns 64x64
  const int wc   = wid & 1;
  const int z    = blockIdx.z;
  const long K   = p.K;

  int bx = blockIdx.x, by = blockIdx.y;
  if constexpr (SWZ) {  // bijective XCD swizzle (m204), column-major flatten
    const int gx = gridDim.x, gy = gridDim.y;
    const int nwg = gx * gy;
    const int id = bx * gy + by;
    const int q = nwg >> 3, r = nwg & 7;
    const int xcd = id & 7, loc = id >> 3;
    const int nid = (xcd < r ? xcd * (q + 1) : r * (q + 1) + (xcd - r) * q) + loc;
    bx = nid / gy; by = nid % gy;
  }

  const long am0 = (long)by * 128;
  const long bn0 = (long)bx * 128;

  int cntE = 0;
  const int* il = nullptr;
  if constexpr (SPARSE) {
    cntE = p.cnt[p.ebase + z];
    if (am0 >= cntE) return;  // wave-uniform early exit (before any barrier)
    il = p.idx + (long)(p.ebase + z) * 2048;
  }

  // per-thread staging sources: chunk c covers row (c>>2), 16B piece (c&3)
  const int c0 = wid * 64 + lane;
  const int c1 = 256 + wid * 64 + lane;
  const bf16 *aS0, *aS1, *bS0, *bS1;
  const bf16 *aL0 = nullptr, *aL1 = nullptr, *bL0 = nullptr, *bL1 = nullptr;
  {
    const bf16* Bb = p.Bh + (long)z * p.bBS + bn0 * K;
    bS0 = Bb + (long)(c0 >> 2) * K + (c0 & 3) * 8;
    bS1 = Bb + (long)(c1 >> 2) * K + (c1 & 3) * 8;
    if constexpr (GATHER) {
      const int g0 = (int)am0 + (c0 >> 2);
      const int g1 = (int)am0 + (c1 >> 2);
      const long r0 = il[g0 < cntE ? g0 : 0];
      const long r1 = il[g1 < cntE ? g1 : 0];
      aS0 = p.Ah + r0 * K + (c0 & 3) * 8;
      aS1 = p.Ah + r1 * K + (c1 & 3) * 8;
    } else {
      const bf16* Ab = p.Ah + (long)z * p.aBS + am0 * K;
      aS0 = Ab + (long)(c0 >> 2) * K + (c0 & 3) * 8;
      aS1 = Ab + (long)(c1 >> 2) * K + (c1 & 3) * 8;
    }
    if constexpr (SPLIT) {
      const bf16* Abl = p.Al + (long)z * p.aBS + am0 * K;
      const bf16* Bbl = p.Bl + (long)z * p.bBS + bn0 * K;
      aL0 = Abl + (long)(c0 >> 2) * K + (c0 & 3) * 8;
      aL1 = Abl + (long)(c1 >> 2) * K + (c1 & 3) * 8;
      bL0 = Bbl + (long)(c0 >> 2) * K + (c0 & 3) * 8;
      bL1 = Bbl + (long)(c1 >> 2) * K + (c1 & 3) * 8;
    }
  }
  char* dst0 = (char*)(void*)lds + (wid * 64) * 16;        // + lane*16 by HW
  char* dst1 = (char*)(void*)lds + (256 + wid * 64) * 16;

  f32x4 acc[4][4] = {};

  const int aoff = (wr * 64 + (lane & 15)) * 32 + (lane >> 4) * 8;
  const int boff = (wc * 64 + (lane & 15)) * 32 + (lane >> 4) * 8;

  for (long k0 = 0; k0 < K; k0 += 32) {
    __syncthreads();
    GLOAD_LDS16(aS0 + k0, dst0);
    GLOAD_LDS16(aS1 + k0, dst1);
    GLOAD_LDS16(bS0 + k0, dst0 + 8192);
    GLOAD_LDS16(bS1 + k0, dst1 + 8192);
    if constexpr (SPLIT) {
      GLOAD_LDS16(aL0 + k0, dst0 + 16384);
      GLOAD_LDS16(aL1 + k0, dst1 + 16384);
      GLOAD_LDS16(bL0 + k0, dst0 + 24576);
      GLOAD_LDS16(bL1 + k0, dst1 + 24576);
    }
    __syncthreads();

    bf16x8 ah[4], bh[4];
#pragma unroll
    for (int m = 0; m < 4; ++m) ah[m] = *(const bf16x8*)(ldsAh + aoff + m * 512);
#pragma unroll
    for (int n = 0; n < 4; ++n) bh[n] = *(const bf16x8*)(ldsBh + boff + n * 512);
    if constexpr (SPLIT) {
      bf16x8 al[4], bl[4];
#pragma unroll
      for (int m = 0; m < 4; ++m) al[m] = *(const bf16x8*)(ldsAl + aoff + m * 512);
#pragma unroll
      for (int n = 0; n < 4; ++n) bl[n] = *(const bf16x8*)(ldsBl + boff + n * 512);
#pragma unroll
      for (int m = 0; m < 4; ++m)
#pragma unroll
        for (int n = 0; n < 4; ++n) {
          acc[m][n] = __builtin_amdgcn_mfma_f32_16x16x32_bf16(ah[m], bh[n], acc[m][n], 0, 0, 0);
          acc[m][n] = __builtin_amdgcn_mfma_f32_16x16x32_bf16(ah[m], bl[n], acc[m][n], 0, 0, 0);
          acc[m][n] = __builtin_amdgcn_mfma_f32_16x16x32_bf16(al[m], bh[n], acc[m][n], 0, 0, 0);
        }
    } else {
#pragma unroll
      for (int m = 0; m < 4; ++m)
#pragma unroll
        for (int n = 0; n < 4; ++n)
          acc[m][n] = __builtin_amdgcn_mfma_f32_16x16x32_bf16(ah[m], bh[n], acc[m][n], 0, 0, 0);
    }
  }

  const float* bias = p.bias + (long)z * p.biasBS;
  const long N = p.N;

#pragma unroll
  for (int m = 0; m < 4; ++m) {
#pragma unroll
    for (int n = 0; n < 4; ++n) {
      const long col = bn0 + wc * 64 + n * 16 + (lane & 15);
      const float bv = bias[col];
#pragma unroll
      for (int r = 0; r < 4; ++r) {
        const long row = am0 + wr * 64 + m * 16 + (lane >> 4) * 4 + r;
        float v = acc[m][n][r] + bv;
        if constexpr (EPI == EPI_GELU_SPLIT) {
          float g = gelu_precise(v);
          bf16 h = (bf16)g;
          long o = row * N + col;
          p.outH[o] = h;
          p.outL[o] = (bf16)(g - (float)h);
        } else if constexpr (EPI == EPI_RESID) {
          long o = row * N + col;
          p.outF[o] = p.resid[o] + v;   // in-place safe: 1 thread per element
        } else if constexpr (EPI == EPI_GELU_BF16) {
          long o = (long)z * p.outBS + row * N + col;
          p.outH[o] = (bf16)gelu_fast(v);
        } else if constexpr (EPI == EPI_MOE) {
          if (row < cntE) {
            const int tok = il[row];
            const float wgt = p.rwp[(long)tok * 8 + p.ebase + z];
            atomicAdd(p.outF + (long)tok * N + col, wgt * v);
          }
        } else {  // EPI_BIAS
          p.outF[row * N + col] = v;
        }
      }
    }
  }
}

// ------------- transpose fp32 [R][C] -> bf16 [C][R] (optional lo split) -------------
template <bool SPLITOUT>
__global__ void transpose_cvt(const float* __restrict__ in, bf16* __restrict__ outh,
                              bf16* __restrict__ outl, int R, int C, long inBS, long outBS) {
  __shared__ float tile[32][33];
  const float* inp = in + (long)blockIdx.z * inBS;
  const long c0 = (long)blockIdx.x * 32;
  const long r0 = (long)blockIdx.y * 32;
  const int tx = threadIdx.x;  // 32
  const int ty = threadIdx.y;  // 8
#pragma unroll
  for (int i = 0; i < 4; ++i) {
    int r = ty + i * 8;
    tile[r][tx] = inp[(r0 + r) * (long)C + c0 + tx];
  }
  __syncthreads();
  const long ob = (long)blockIdx.z * outBS;
#pragma unroll
  for (int i = 0; i < 4; ++i) {
    int c = ty + i * 8;
    float v = tile[tx][c];
    bf16 h = (bf16)v;
    long o = ob + (c0 + c) * (long)R + r0 + tx;
    outh[o] = h;
    if constexpr (SPLITOUT) outl[o] = (bf16)(v - (float)h);
  }
}

// ------------- embedding gather -------------
__global__ void embed_kernel(const int* __restrict__ ids, const float* __restrict__ emb,
                             float* __restrict__ x) {
  const long t = blockIdx.x;
  const int id = ids[t];
  ((float4*)(x + t * 1024))[threadIdx.x] = ((const float4*)(emb + (long)id * 1024))[threadIdx.x];
}

// ------------- LayerNorm -> bf16 hi/lo split -------------
__global__ void ln_split_kernel(const float* __restrict__ x, const float* __restrict__ sc,
                                const float* __restrict__ bi, bf16* __restrict__ oh,
                                bf16* __restrict__ ol) {
  const long t = blockIdx.x;
  const int tid = threadIdx.x;  // 256
  const int lane = tid & 63, wid = tid >> 6;
  float4 a = ((const float4*)(x + t * 1024))[tid];
  float s = a.x + a.y + a.z + a.w;
  float q = a.x * a.x + a.y * a.y + a.z * a.z + a.w * a.w;
#pragma unroll
  for (int off = 32; off; off >>= 1) {
    s += __shfl_down(s, off);
    q += __shfl_down(q, off);
  }
  __shared__ float sr[4], qr[4];
  if (lane == 0) { sr[wid] = s; qr[wid] = q; }
  __syncthreads();
  s = sr[0] + sr[1] + sr[2] + sr[3];
  q = qr[0] + qr[1] + qr[2] + qr[3];
  const float mu = s * (1.0f / 1024.0f);
  const float var = q * (1.0f / 1024.0f) - mu * mu;
  const float rs = rsqrtf(var + 1e-5f);
#pragma unroll
  for (int j = 0; j < 4; ++j) {
    const int d = tid * 4 + j;
    const float g = (((const float*)&a)[j] - mu) * rs * sc[d] + bi[d];
    const bf16 h = (bf16)g;
    oh[t * 1024 + d] = h;
    ol[t * 1024 + d] = (bf16)(g - (float)h);
  }
}

// ------------- router: logits, top-2 softmax, scatter + top2 record -------------
__global__ void router_kernel(const float* __restrict__ x, const float* __restrict__ Wr,
                              const float* __restrict__ br, float* __restrict__ rwo,
                              int* __restrict__ top2) {
  const long t = blockIdx.x;
  const int lane = threadIdx.x;  // 64
  float acc[8];
#pragma unroll
  for (int e = 0; e < 8; ++e) acc[e] = 0.0f;
  const float4* xr = (const float4*)(x + t * 1024);
#pragma unroll
  for (int j = 0; j < 4; ++j) {
    const int d4 = j * 64 + lane;
    float4 xv = xr[d4];
#pragma unroll
    for (int u = 0; u < 4; ++u) {
      const float xs = ((const float*)&xv)[u];
      const float4* wp = (const float4*)(Wr + (long)(d4 * 4 + u) * 8);
      float4 w0 = wp[0], w1 = wp[1];
      acc[0] += xs * w0.x; acc[1] += xs * w0.y; acc[2] += xs * w0.z; acc[3] += xs * w0.w;
      acc[4] += xs * w1.x; acc[5] += xs * w1.y; acc[6] += xs * w1.z; acc[7] += xs * w1.w;
    }
  }
#pragma unroll
  for (int off = 32; off; off >>= 1)
#pragma unroll
    for (int e = 0; e < 8; ++e) acc[e] += __shfl_down(acc[e], off);
  if (lane == 0) {
    float v[8];
#pragma unroll
    for (int e = 0; e < 8; ++e) v[e] = acc[e] + br[e];
    int i0 = 0; float v0 = v[0];
    for (int e = 1; e < 8; ++e) if (v[e] > v0) { v0 = v[e]; i0 = e; }
    int i1 = -1; float v1 = -3.4e38f;
    for (int e = 0; e < 8; ++e) if (e != i0 && v[e] > v1) { v1 = v[e]; i1 = e; }
    float e1 = expf(v1 - v0);
    float den = 1.0f + e1;
    float w0 = 1.0f / den, w1 = e1 / den;
    float* o = rwo + t * 8;
#pragma unroll
    for (int e = 0; e < 8; ++e) o[e] = (e == i0) ? w0 : (e == i1 ? w1 : 0.0f);
    top2[t] = i0 | (i1 << 8);
  }
}

// ------------- per-expert token list build (order-free; outputs order-invariant) ------
__global__ void build_lists(const int* __restrict__ top2, int* __restrict__ cnt,
                            int* __restrict__ idx) {
  const int t = blockIdx.x * 256 + threadIdx.x;
  const int rec = top2[t];
  const int e0 = rec & 255, e1 = (rec >> 8) & 255;
  int p0 = atomicAdd(&cnt[e0], 1);
  idx[e0 * 2048 + p0] = t;
  int p1 = atomicAdd(&cnt[e1], 1);
  idx[e1 * 2048 + p1] = t;
}

// ------------- fp32 -> bf16 flat convert -------------
__global__ void cvt_bf16_kernel(const float* __restrict__ in, bf16* __restrict__ out, long n) {
  long i = ((long)blockIdx.x * blockDim.x + threadIdx.x) * 8;
  if (i >= n) return;
  float4 a = *(const float4*)(in + i);
  float4 b = *(const float4*)(in + i + 4);
  bf16x8 o;
  o[0] = (bf16)a.x; o[1] = (bf16)a.y; o[2] = (bf16)a.z; o[3] = (bf16)a.w;
  o[4] = (bf16)b.x; o[5] = (bf16)b.y; o[6] = (bf16)b.z; o[7] = (bf16)b.w;
  *(bf16x8*)(out + i) = o;
}

// ---------------- host launch ----------------
extern "C" void kernel_launch(void* const* d_in, const int* in_sizes, int n_in,
                              void* d_out, int out_size, void* d_ws, size_t ws_size,
                              hipStream_t stream) {
  (void)in_sizes; (void)n_in; (void)out_size; (void)ws_size;
  const int*   ids  = (const int*)d_in[0];
  const float* emb  = (const float*)d_in[1];
  const float* tlns = (const float*)d_in[2];
  const float* tlnb = (const float*)d_in[3];
  const float* tw1  = (const float*)d_in[4];
  const float* tb1  = (const float*)d_in[5];
  const float* tw2  = (const float*)d_in[6];
  const float* tb2  = (const float*)d_in[7];
  const float* Wr   = (const float*)d_in[8];
  const float* br   = (const float*)d_in[9];
  const float* ew1  = (const float*)d_in[10];
  const float* eb1  = (const float*)d_in[11];
  const float* ew2  = (const float*)d_in[12];
  const float* eb2  = (const float*)d_in[13];
  const float* Wl   = (const float*)d_in[14];
  const float* bl   = (const float*)d_in[15];

  float* logits = (float*)d_out;
  float* rwout  = (float*)d_out + (long)Tm * Vm;

  // ws arena (~167 MiB) with phase-based region reuse
  size_t off = 0;
  auto take = [&](size_t bytes) {
    void* pp = (char*)d_ws + off;
    off += (bytes + 255) & ~(size_t)255;
    return pp;
  };
  float* X    = (float*)take((size_t)Tm * Dm * 4);
  bf16*  XB   = (bf16*) take((size_t)Tm * Dm * 2);
  float* Y    = (float*)take((size_t)Tm * Dm * 4);
  bf16*  YB   = (bf16*) take((size_t)Tm * Dm * 2);
  bf16*  Breg = (bf16*) take((size_t)4 * DFFm * Dm * 2);                    // 33.5MB
  bf16*  Creg = (bf16*) take((size_t)(2L * Tm * Dm + 2L * Tm * DFFm) * 2);  // 42MB
  bf16*  Dreg = (bf16*) take((size_t)4 * Tm * DFFm * 2);                    // 67MB
  int*   top2 = (int*)  take((size_t)Tm * 4);
  int*   cnt  = (int*)  take(8 * 4);
  int*   idxl = (int*)  take((size_t)8 * Tm * 4);

  bf16* TW1h = Breg;
  bf16* TW1l = Breg + (long)DFFm * Dm;
  bf16* TW2h = Breg + 2L * DFFm * Dm;
  bf16* TW2l = Breg + 3L * DFFm * Dm;
  bf16* EW1T = Breg;                 // reuse (4 experts x [4096][1024])
  bf16* HLNh = Creg;
  bf16* HLNl = Creg + (long)Tm * Dm;
  bf16* HTh  = Creg + 2L * Tm * Dm;
  bf16* HTl  = HTh + (long)Tm * DFFm;
  bf16* EW2T = Creg;                 // reuse (4 experts x [1024][4096])
  bf16* HE   = Dreg;                 // 4 experts x [2048 list rows][4096]
  bf16* WLT  = Dreg;                 // reuse: [32000][1024]

  embed_kernel<<<dim3(Tm), dim3(256), 0, stream>>>(ids, emb, X);

  // ---- temporal residual MLP blocks (fp32-accurate via bf16 hi/lo split) ----
  for (int l = 0; l < 2; ++l) {
    transpose_cvt<true><<<dim3(DFFm / 32, Dm / 32, 1), dim3(32, 8), 0, stream>>>(
        tw1 + (long)l * Dm * DFFm, TW1h, TW1l, Dm, DFFm, 0, 0);
    transpose_cvt<true><<<dim3(Dm / 32, DFFm / 32, 1), dim3(32, 8), 0, stream>>>(
        tw2 + (long)l * DFFm * Dm, TW2h, TW2l, DFFm, Dm, 0, 0);
    ln_split_kernel<<<dim3(Tm), dim3(256), 0, stream>>>(X, tlns + l * Dm, tlnb + l * Dm,
                                                        HLNh, HLNl);
    GemmP p1{};
    p1.Ah = HLNh; p1.Al = HLNl; p1.Bh = TW1h; p1.Bl = TW1l;
    p1.bias = tb1 + (long)l * DFFm;
    p1.outH = HTh; p1.outL = HTl;
    p1.K = Dm; p1.N = DFFm;
    gemm_bt<EPI_GELU_SPLIT, true, false, false>
        <<<dim3(DFFm / 128, Tm / 128, 1), dim3(256), 0, stream>>>(p1);

    GemmP p2{};
    p2.Ah = HTh; p2.Al = HTl; p2.Bh = TW2h; p2.Bl = TW2l;
    p2.bias = tb2 + (long)l * Dm;
    p2.resid = X; p2.outF = X;
    p2.K = DFFm; p2.N = Dm;
    gemm_bt<EPI_RESID, true, false, false>
        <<<dim3(Dm / 128, Tm / 128, 1), dim3(256), 0, stream>>>(p2);
  }

  // ---- router (fp32) + token lists ----
  router_kernel<<<dim3(Tm), dim3(64), 0, stream>>>(X, Wr, br, rwout, top2);
  hipMemsetAsync(cnt, 0, 8 * 4, stream);
  build_lists<<<dim3(Tm / 256), dim3(256), 0, stream>>>(top2, cnt, idxl);
  cvt_bf16_kernel<<<dim3(Tm * Dm / (256 * 8)), dim3(256), 0, stream>>>(X, XB, (long)Tm * Dm);
  hipMemsetAsync(Y, 0, (size_t)Tm * Dm * 4, stream);

  // ---- sparse top-2 expert stack, 2 quads of 4 experts (bf16) ----
  for (int q = 0; q < 2; ++q) {
    transpose_cvt<false><<<dim3(DFFm / 32, Dm / 32, 4), dim3(32, 8), 0, stream>>>(
        ew1 + (long)q * 4 * Dm * DFFm, EW1T, nullptr, Dm, DFFm, (long)Dm * DFFm,
        (long)DFFm * Dm);
    transpose_cvt<false><<<dim3(Dm / 32, DFFm / 32, 4), dim3(32, 8), 0, stream>>>(
        ew2 + (long)q * 4 * DFFm * Dm, EW2T, nullptr, DFFm, Dm, (long)DFFm * Dm,
        (long)Dm * DFFm);

    GemmP pe1{};
    pe1.Ah = XB; pe1.Bh = EW1T;
    pe1.bias = eb1 + (long)q * 4 * DFFm; pe1.biasBS = DFFm;
    pe1.outH = HE; pe1.outBS = (long)Tm * DFFm;
    pe1.aBS = 0; pe1.bBS = (long)DFFm * Dm;
    pe1.cnt = cnt; pe1.idx = idxl; pe1.ebase = q * 4;
    pe1.K = Dm; pe1.N = DFFm;
    gemm_bt<EPI_GELU_BF16, false, true, false>
        <<<dim3(DFFm / 128, Tm / 128, 4), dim3(256), 0, stream>>>(pe1);

    GemmP pe2{};
    pe2.Ah = HE; pe2.aBS = (long)Tm * DFFm;
    pe2.Bh = EW2T; pe2.bBS = (long)Dm * DFFm;
    pe2.bias = eb2 + (long)q * 4 * Dm; pe2.biasBS = Dm;
    pe2.rwp = rwout; pe2.cnt = cnt; pe2.idx = idxl; pe2.ebase = q * 4;
    pe2.outF = Y;
    pe2.K = DFFm; pe2.N = Dm;
    gemm_bt<EPI_MOE, false, false, false>
        <<<dim3(Dm / 128, Tm / 128, 4), dim3(256), 0, stream>>>(pe2);
  }

  // ---- final logits GEMM ----
  cvt_bf16_kernel<<<dim3(Tm * Dm / (256 * 8)), dim3(256), 0, stream>>>(Y, YB, (long)Tm * Dm);
  transpose_cvt<false><<<dim3(Vm / 32, Dm / 32, 1), dim3(32, 8), 0, stream>>>(
      Wl, WLT, nullptr, Dm, Vm, 0, 0);
  GemmP pl{};
  pl.Ah = YB; pl.Bh = WLT; pl.bias = bl;
  pl.outF = logits;
  pl.K = Dm; pl.N = Vm;
  gemm_bt<EPI_BIAS, false, false, true>
      <<<dim3(Vm / 128, Tm / 128, 1), dim3(256), 0, stream>>>(pl);
}